// Round 1
// baseline (389.237 us; speedup 1.0000x reference)
//
#include <hip/hip_runtime.h>
#include <hip/hip_bf16.h>

#define BB 4
#define CC 128
#define HH 64
#define WW 64
#define HWSZ 4096
#define LL 4096
#define DI 256
#define DS 16
#define DR 8
#define NDBL 40
#define NCHUNK 64
#define CLEN 64

__device__ __forceinline__ float silu_f(float x) {
    return x / (1.f + __expf(-x));
}
__device__ __forceinline__ float softplus_f(float x) {
    return (x > 20.f) ? x : log1pf(__expf(x));
}

// ---------------- Generic 128x128-tile fp32 GEMM ----------------
// C[m,n] = sum_k A[m,k] * B(n,k)   where B is either [N,K] row-major (BKN=0)
// or [K,N] row-major (BKN=1, i.e. NN gemm).
// EPI: 0 = plain, 1 = +bias[m], 2 = +bias[m] + res_x + res_g (final output)
template<int EPI, int BKN>
__global__ __launch_bounds__(256) void gemm128(
    const float* __restrict__ Ap, int lda, long aStr,
    const float* __restrict__ Bp, int ldb, long bStr,
    float* __restrict__ Cp, int ldc, long cStr,
    int Msz, int Nsz, int Ksz,
    const float* __restrict__ bias,
    const float* __restrict__ res_x,
    const float* __restrict__ res_g)
{
    __shared__ float Al[32][132];
    __shared__ float Bl[32][132];
    const int tid = threadIdx.x;
    const int z = blockIdx.z;
    const int m0 = blockIdx.y * 128;
    const int n0 = blockIdx.x * 128;
    const float* A = Ap + (long)z * aStr;
    const float* Bm = Bp + (long)z * bStr;
    float* Cc = Cp + (long)z * cStr;
    const int ty = tid / 16, tx = tid % 16;

    float acc[2][2][4][4];
#pragma unroll
    for (int ii = 0; ii < 2; ++ii)
#pragma unroll
        for (int jj = 0; jj < 2; ++jj)
#pragma unroll
            for (int i = 0; i < 4; ++i)
#pragma unroll
                for (int j = 0; j < 4; ++j) acc[ii][jj][i][j] = 0.f;

    for (int kc = 0; kc < Ksz; kc += 32) {
        // stage A [m-tile][32k] -> Al[k][m]
        {
            int r = tid / 8;
            int c4 = (tid % 8) * 4;
#pragma unroll
            for (int p = 0; p < 4; ++p) {
                int ml = r + p * 32;
                int m = m0 + ml;
                float4 v = make_float4(0.f, 0.f, 0.f, 0.f);
                if (m < Msz) v = *(const float4*)&A[(long)m * lda + kc + c4];
                Al[c4 + 0][ml] = v.x;
                Al[c4 + 1][ml] = v.y;
                Al[c4 + 2][ml] = v.z;
                Al[c4 + 3][ml] = v.w;
            }
        }
        if (BKN == 0) {
            int r = tid / 8;
            int c4 = (tid % 8) * 4;
#pragma unroll
            for (int p = 0; p < 4; ++p) {
                int nl = r + p * 32;
                int n = n0 + nl;
                float4 v = make_float4(0.f, 0.f, 0.f, 0.f);
                if (n < Nsz) v = *(const float4*)&Bm[(long)n * ldb + kc + c4];
                Bl[c4 + 0][nl] = v.x;
                Bl[c4 + 1][nl] = v.y;
                Bl[c4 + 2][nl] = v.z;
                Bl[c4 + 3][nl] = v.w;
            }
        } else {
            int k = tid / 32;
            int n4 = (tid % 32) * 4;
#pragma unroll
            for (int p = 0; p < 4; ++p) {
                int kk = k + p * 8;
                float4 v = make_float4(0.f, 0.f, 0.f, 0.f);
                int n = n0 + n4;
                if (n + 3 < Nsz) {
                    v = *(const float4*)&Bm[(long)(kc + kk) * ldb + n];
                } else {
                    float tmp[4] = {0.f, 0.f, 0.f, 0.f};
                    for (int e = 0; e < 4; ++e)
                        if (n + e < Nsz) tmp[e] = Bm[(long)(kc + kk) * ldb + n + e];
                    v = make_float4(tmp[0], tmp[1], tmp[2], tmp[3]);
                }
                *(float4*)&Bl[kk][n4] = v;
            }
        }
        __syncthreads();
#pragma unroll 8
        for (int k = 0; k < 32; ++k) {
            float4 a0 = *(const float4*)&Al[k][ty * 4];
            float4 a1 = *(const float4*)&Al[k][ty * 4 + 64];
            float4 b0 = *(const float4*)&Bl[k][tx * 4];
            float4 b1 = *(const float4*)&Bl[k][tx * 4 + 64];
            float av[2][4] = {{a0.x, a0.y, a0.z, a0.w}, {a1.x, a1.y, a1.z, a1.w}};
            float bv[2][4] = {{b0.x, b0.y, b0.z, b0.w}, {b1.x, b1.y, b1.z, b1.w}};
#pragma unroll
            for (int ii = 0; ii < 2; ++ii)
#pragma unroll
                for (int jj = 0; jj < 2; ++jj)
#pragma unroll
                    for (int i = 0; i < 4; ++i)
#pragma unroll
                        for (int j = 0; j < 4; ++j)
                            acc[ii][jj][i][j] += av[ii][i] * bv[jj][j];
        }
        __syncthreads();
    }

#pragma unroll
    for (int ii = 0; ii < 2; ++ii)
#pragma unroll
        for (int i = 0; i < 4; ++i) {
            int m = m0 + ty * 4 + i + 64 * ii;
            if (m >= Msz) continue;
            float bval = 0.f;
            if (EPI >= 1) bval = bias[m];
#pragma unroll
            for (int jj = 0; jj < 2; ++jj) {
                int n = n0 + tx * 4 + 64 * jj;
                if (n >= Nsz) continue;
                float4 v = make_float4(acc[ii][jj][i][0], acc[ii][jj][i][1],
                                       acc[ii][jj][i][2], acc[ii][jj][i][3]);
                if (EPI >= 1) { v.x += bval; v.y += bval; v.z += bval; v.w += bval; }
                if (EPI == 2) {
                    float4 rx = *(const float4*)&res_x[((long)z * CC + m) * HWSZ + n];
                    float4 rg = *(const float4*)&res_g[(long)m * (BB * HWSZ) + (long)z * HWSZ + n];
                    v.x += rx.x + rg.x; v.y += rx.y + rg.y;
                    v.z += rx.z + rg.z; v.w += rx.w + rg.w;
                }
                if (n + 3 < Nsz) {
                    *(float4*)&Cc[(long)m * ldc + n] = v;
                } else {
                    float tmp[4] = {v.x, v.y, v.z, v.w};
                    for (int e = 0; e < 4; ++e)
                        if (n + e < Nsz) Cc[(long)m * ldc + n + e] = tmp[e];
                }
            }
        }
}

// ---------------- M = cv2_w[:,128:] @ out_proj_w  (128x256) ----------------
__global__ void computeM_kernel(const float* __restrict__ cv2_w,
                                const float* __restrict__ opw,
                                float* __restrict__ Mm)
{
    int o = blockIdx.x;
    int d = threadIdx.x;
    float acc = 0.f;
#pragma unroll 8
    for (int i = 0; i < CC; ++i)
        acc += cv2_w[o * 256 + 128 + i] * opw[i * 256 + d];
    Mm[o * 256 + d] = acc;
}

// ---------------- transpose + LayerNorm:  t_ln[b,l,c] ----------------
__global__ __launch_bounds__(256) void ln_kernel(const float* __restrict__ xh,
                                                 const float* __restrict__ ln_g,
                                                 const float* __restrict__ ln_b,
                                                 float* __restrict__ t_ln)
{
    __shared__ float tile[128][65];
    __shared__ float red[8][64];
    __shared__ float mean_s[64], inv_s[64];
    int b = blockIdx.y;
    int l0 = blockIdx.x * 64;
    int t = threadIdx.x;
#pragma unroll 4
    for (int p = 0; p < 32; ++p) {
        int c = (t / 64) + p * 4;
        tile[c][t % 64] = xh[((long)b * CC + c) * HWSZ + l0 + (t % 64)];
    }
    __syncthreads();
    int lc = t % 64, cg = t / 64;
    float s1 = 0.f, s2 = 0.f;
#pragma unroll 8
    for (int i = 0; i < 32; ++i) {
        float v = tile[cg * 32 + i][lc];
        s1 += v; s2 += v * v;
    }
    red[cg][lc] = s1;
    red[4 + cg][lc] = s2;
    __syncthreads();
    if (t < 64) {
        float m = (red[0][t] + red[1][t] + red[2][t] + red[3][t]) * (1.f / 128.f);
        float q = (red[4][t] + red[5][t] + red[6][t] + red[7][t]) * (1.f / 128.f);
        mean_s[t] = m;
        inv_s[t] = rsqrtf(q - m * m + 1e-5f);
    }
    __syncthreads();
#pragma unroll 4
    for (int p = 0; p < 32; ++p) {
        int c = t % 128;
        int lw = t / 128 + p * 2;
        float v = (tile[c][lw] - mean_s[lw]) * inv_s[lw] * ln_g[c] + ln_b[c];
        t_ln[((long)(b * LL + l0 + lw)) * CC + c] = v;
    }
}

// ---------------- local branch: dw3x3 + BN + SiLU ----------------
__global__ void dwconv_kernel(const float* __restrict__ xh,
                              const float* __restrict__ w9,
                              const float* __restrict__ bn_g,
                              const float* __restrict__ bn_b,
                              const float* __restrict__ bn_m,
                              const float* __restrict__ bn_v,
                              float* __restrict__ lbuf)
{
    long idx = (long)blockIdx.x * 256 + threadIdx.x;
    int hw = idx & (HWSZ - 1);
    int bc = idx >> 12;
    int c = bc & (CC - 1);
    int i = hw >> 6, j = hw & 63;
    const float* base = xh + (long)bc * HWSZ;
    float acc = 0.f;
#pragma unroll
    for (int u = 0; u < 3; ++u) {
        int ii = i + u - 1;
        if (ii < 0 || ii >= HH) continue;
#pragma unroll
        for (int v = 0; v < 3; ++v) {
            int jj = j + v - 1;
            if (jj < 0 || jj >= WW) continue;
            acc += base[ii * WW + jj] * w9[c * 9 + u * 3 + v];
        }
    }
    float sc = bn_g[c] * rsqrtf(bn_v[c] + 1e-5f);
    float val = (acc - bn_m[c]) * sc + bn_b[c];
    lbuf[idx] = silu_f(val);
}

// ---------------- causal depthwise conv1d (DC=4) + SiLU ----------------
__global__ void conv1d_kernel(const float* __restrict__ xz,
                              const float* __restrict__ cw,
                              const float* __restrict__ cb,
                              float* __restrict__ xm_act)
{
    int m = blockIdx.x;          // b*L + l
    int l = m & (LL - 1);
    int d = threadIdx.x;
    float acc = cb[d];
#pragma unroll
    for (int k = 0; k < 4; ++k) {
        int li = l + k - 3;
        if (li >= 0) acc += xz[((long)(m + k - 3)) * 512 + d] * cw[d * 4 + k];
    }
    xm_act[(long)m * DI + d] = silu_f(acc);
}

// ---------------- dt = softplus(dbl[:, :8] @ dt_proj_w^T + b) ----------------
__global__ void dt_kernel(const float* __restrict__ dbl,
                          const float* __restrict__ dpw,
                          const float* __restrict__ dpb,
                          float* __restrict__ dt_full)
{
    int m = blockIdx.x;
    int d = threadIdx.x;
    float acc = dpb[d];
#pragma unroll
    for (int r = 0; r < DR; ++r)
        acc += dbl[(long)m * NDBL + r] * dpw[d * DR + r];
    dt_full[(long)m * DI + d] = softplus_f(acc);
}

// ---------------- chunked selective scan ----------------
// phase A: per-chunk partial state (h from 0) and product of dA
__global__ __launch_bounds__(256) void scanA_kernel(const float* __restrict__ dt_full,
                                                    const float* __restrict__ xm_act,
                                                    const float* __restrict__ dbl,
                                                    const float* __restrict__ A_log,
                                                    float* __restrict__ hend,
                                                    float* __restrict__ Pp)
{
    int chunk = blockIdx.x;
    int dgrp = blockIdx.y;
    int b = blockIdx.z;
    int tid = threadIdx.x;
    int dl = tid / 16, s = tid % 16;
    int d = dgrp * 16 + dl;
    float a = -__expf(A_log[d * DS + s]);
    float h = 0.f, P = 1.f;
    long mBase = (long)b * LL + chunk * CLEN;
    for (int l = 0; l < CLEN; ++l) {
        long m = mBase + l;
        float dt = dt_full[m * DI + d];
        float xm = xm_act[m * DI + d];
        float Bv = dbl[m * NDBL + DR + s];
        float da = __expf(dt * a);
        h = da * h + (dt * xm) * Bv;
        P *= da;
    }
    long o = ((long)(b * NCHUNK + chunk)) * 4096 + dgrp * 256 + tid;
    hend[o] = h;
    Pp[o] = P;
}

// phase B: sequential combine across chunks (tiny)
__global__ __launch_bounds__(256) void scanB_kernel(const float* __restrict__ hend,
                                                    const float* __restrict__ Pp,
                                                    float* __restrict__ hinit)
{
    int dgrp = blockIdx.x;
    int b = blockIdx.y;
    int tid = threadIdx.x;
    long col = dgrp * 256 + tid;
    float hi = 0.f;
    for (int c = 0; c < NCHUNK; ++c) {
        long o = ((long)(b * NCHUNK + c)) * 4096 + col;
        hinit[o] = hi;
        hi = Pp[o] * hi + hend[o];
    }
}

// phase C: recompute with correct initial state, emit gated output yg
__global__ __launch_bounds__(256) void scanC_kernel(const float* __restrict__ dt_full,
                                                    const float* __restrict__ xm_act,
                                                    const float* __restrict__ dbl,
                                                    const float* __restrict__ xz,
                                                    const float* __restrict__ A_log,
                                                    const float* __restrict__ Dp,
                                                    const float* __restrict__ hinit,
                                                    float* __restrict__ yg)
{
    int chunk = blockIdx.x;
    int dgrp = blockIdx.y;
    int b = blockIdx.z;
    int tid = threadIdx.x;
    int dl = tid / 16, s = tid % 16;
    int d = dgrp * 16 + dl;
    float a = -__expf(A_log[d * DS + s]);
    float Dd = Dp[d];
    long o = ((long)(b * NCHUNK + chunk)) * 4096 + dgrp * 256 + tid;
    float h = hinit[o];
    long mBase = (long)b * LL + chunk * CLEN;
    for (int l = 0; l < CLEN; ++l) {
        long m = mBase + l;
        float dt = dt_full[m * DI + d];
        float xm = xm_act[m * DI + d];
        float Bv = dbl[m * NDBL + DR + s];
        float Cv = dbl[m * NDBL + DR + DS + s];
        float da = __expf(dt * a);
        h = da * h + (dt * xm) * Bv;
        float p = h * Cv;
        p += __shfl_xor(p, 1);
        p += __shfl_xor(p, 2);
        p += __shfl_xor(p, 4);
        p += __shfl_xor(p, 8);
        if (s == 0) {
            float zv = xz[m * 512 + 256 + d];
            float y = p + xm * Dd;
            yg[m * DI + d] = y * silu_f(zv);
        }
    }
}

extern "C" void kernel_launch(void* const* d_in, const int* in_sizes, int n_in,
                              void* d_out, int out_size, void* d_ws, size_t ws_size,
                              hipStream_t stream)
{
    const float* x        = (const float*)d_in[0];
    const float* cv1_w    = (const float*)d_in[1];
    const float* cv1_b    = (const float*)d_in[2];
    const float* dw_w     = (const float*)d_in[3];
    const float* bn_g     = (const float*)d_in[4];
    const float* bn_b     = (const float*)d_in[5];
    const float* bn_m     = (const float*)d_in[6];
    const float* bn_v     = (const float*)d_in[7];
    const float* ln_g     = (const float*)d_in[8];
    const float* ln_b     = (const float*)d_in[9];
    const float* in_proj_w = (const float*)d_in[10];
    const float* conv1d_w = (const float*)d_in[11];
    const float* conv1d_b = (const float*)d_in[12];
    const float* x_proj_w = (const float*)d_in[13];
    const float* dt_proj_w = (const float*)d_in[14];
    const float* dt_proj_b = (const float*)d_in[15];
    const float* A_log    = (const float*)d_in[16];
    const float* Dp       = (const float*)d_in[17];
    const float* out_proj_w = (const float*)d_in[18];
    const float* cv2_w    = (const float*)d_in[19];
    const float* cv2_b    = (const float*)d_in[20];
    float* out = (float*)d_out;

    float* ws = (float*)d_ws;
    float* xh     = ws;                  // 2,097,152
    float* t_ln   = xh + 2097152;        // 2,097,152
    float* l_buf  = t_ln + 2097152;      // 2,097,152
    float* xz     = l_buf + 2097152;     // 8,388,608
    float* xm_act = xz + 8388608;        // 4,194,304
    float* dbl    = xm_act + 4194304;    // 655,360
    float* dt_f   = dbl + 655360;        // 4,194,304
    float* yg     = dt_f + 4194304;      // 4,194,304
    float* hend   = yg + 4194304;        // 1,048,576
    float* Pp     = hend + 1048576;      // 1,048,576
    float* hinit  = Pp + 1048576;        // 1,048,576
    float* gpartT = hinit + 1048576;     // 2,097,152
    float* Mm     = gpartT + 2097152;    // 32,768

    // fused cv2-global x out_proj matrix (independent)
    computeM_kernel<<<dim3(128), 256, 0, stream>>>(cv2_w, out_proj_w, Mm);

    // cv1: xh[b,o,hw] = cv1_w @ x[b] + cv1_b   (NN gemm, batched)
    gemm128<1, 1><<<dim3(32, 1, 4), 256, 0, stream>>>(
        cv1_w, 128, 0, x, HWSZ, (long)CC * HWSZ, xh, HWSZ, (long)CC * HWSZ,
        128, HWSZ, 128, cv1_b, nullptr, nullptr);

    // local branch
    dwconv_kernel<<<dim3(8192), 256, 0, stream>>>(xh, dw_w, bn_g, bn_b, bn_m, bn_v, l_buf);

    // transpose + LayerNorm
    ln_kernel<<<dim3(64, 4), 256, 0, stream>>>(xh, ln_g, ln_b, t_ln);

    // in_proj: xz[m, 0:512] = t_ln[m,:] @ in_proj_w^T  (NT gemm)
    gemm128<0, 0><<<dim3(4, 128, 1), 256, 0, stream>>>(
        t_ln, 128, 0, in_proj_w, 128, 0, xz, 512, 0,
        16384, 512, 128, nullptr, nullptr, nullptr);

    // causal depthwise conv1d + silu
    conv1d_kernel<<<dim3(16384), 256, 0, stream>>>(xz, conv1d_w, conv1d_b, xm_act);

    // x_proj: dbl[m, 0:40] = xm_act[m,:] @ x_proj_w^T
    gemm128<0, 0><<<dim3(1, 128, 1), 256, 0, stream>>>(
        xm_act, 256, 0, x_proj_w, 256, 0, dbl, NDBL, 0,
        16384, NDBL, 256, nullptr, nullptr, nullptr);

    // dt
    dt_kernel<<<dim3(16384), 256, 0, stream>>>(dbl, dt_proj_w, dt_proj_b, dt_f);

    // chunked selective scan
    scanA_kernel<<<dim3(NCHUNK, 16, 4), 256, 0, stream>>>(dt_f, xm_act, dbl, A_log, hend, Pp);
    scanB_kernel<<<dim3(16, 4), 256, 0, stream>>>(hend, Pp, hinit);
    scanC_kernel<<<dim3(NCHUNK, 16, 4), 256, 0, stream>>>(dt_f, xm_act, dbl, xz, A_log, Dp, hinit, yg);

    // g_part: gpartT[o, b*hw] = M[o,:] @ yg[m,:]^T  (NT gemm, M rows = 128)
    gemm128<0, 0><<<dim3(128, 1, 1), 256, 0, stream>>>(
        Mm, 256, 0, yg, 256, 0, gpartT, BB * HWSZ, 0,
        128, BB * HWSZ, 256, nullptr, nullptr, nullptr);

    // final: out[b,o,hw] = x + cv2_b[o] + cv2_w[:, :128] @ l_buf[b] + gpartT
    gemm128<2, 1><<<dim3(32, 1, 4), 256, 0, stream>>>(
        cv2_w, 256, 0, l_buf, HWSZ, (long)CC * HWSZ, out, HWSZ, (long)CC * HWSZ,
        128, HWSZ, 128, cv2_b, x, gpartT);
}

// Round 2
// 322.853 us; speedup vs baseline: 1.2056x; 1.2056x over previous
//
#include <hip/hip_runtime.h>
#include <hip/hip_bf16.h>

#define BB 4
#define CC 128
#define HH 64
#define WW 64
#define HWSZ 4096
#define LL 4096
#define DI 256
#define DS 16
#define DR 8
#define NDBL 40
#define NCHUNK 256
#define CLEN 16

__device__ __forceinline__ float silu_f(float x) {
    return x / (1.f + __expf(-x));
}
__device__ __forceinline__ float softplus_f(float x) {
    return (x > 20.f) ? x : log1pf(__expf(x));
}

// ---------------- Generic 128x128-tile fp32 GEMM ----------------
template<int EPI, int BKN>
__global__ __launch_bounds__(256) void gemm128(
    const float* __restrict__ Ap, int lda, long aStr,
    const float* __restrict__ Bp, int ldb, long bStr,
    float* __restrict__ Cp, int ldc, long cStr,
    int Msz, int Nsz, int Ksz,
    const float* __restrict__ bias,
    const float* __restrict__ res_x,
    const float* __restrict__ res_g)
{
    __shared__ float Al[32][132];
    __shared__ float Bl[32][132];
    const int tid = threadIdx.x;
    const int z = blockIdx.z;
    const int m0 = blockIdx.y * 128;
    const int n0 = blockIdx.x * 128;
    const float* A = Ap + (long)z * aStr;
    const float* Bm = Bp + (long)z * bStr;
    float* Cc = Cp + (long)z * cStr;
    const int ty = tid / 16, tx = tid % 16;

    float acc[2][2][4][4];
#pragma unroll
    for (int ii = 0; ii < 2; ++ii)
#pragma unroll
        for (int jj = 0; jj < 2; ++jj)
#pragma unroll
            for (int i = 0; i < 4; ++i)
#pragma unroll
                for (int j = 0; j < 4; ++j) acc[ii][jj][i][j] = 0.f;

    for (int kc = 0; kc < Ksz; kc += 32) {
        {
            int r = tid / 8;
            int c4 = (tid % 8) * 4;
#pragma unroll
            for (int p = 0; p < 4; ++p) {
                int ml = r + p * 32;
                int m = m0 + ml;
                float4 v = make_float4(0.f, 0.f, 0.f, 0.f);
                if (m < Msz) v = *(const float4*)&A[(long)m * lda + kc + c4];
                Al[c4 + 0][ml] = v.x;
                Al[c4 + 1][ml] = v.y;
                Al[c4 + 2][ml] = v.z;
                Al[c4 + 3][ml] = v.w;
            }
        }
        if (BKN == 0) {
            int r = tid / 8;
            int c4 = (tid % 8) * 4;
#pragma unroll
            for (int p = 0; p < 4; ++p) {
                int nl = r + p * 32;
                int n = n0 + nl;
                float4 v = make_float4(0.f, 0.f, 0.f, 0.f);
                if (n < Nsz) v = *(const float4*)&Bm[(long)n * ldb + kc + c4];
                Bl[c4 + 0][nl] = v.x;
                Bl[c4 + 1][nl] = v.y;
                Bl[c4 + 2][nl] = v.z;
                Bl[c4 + 3][nl] = v.w;
            }
        } else {
            int k = tid / 32;
            int n4 = (tid % 32) * 4;
#pragma unroll
            for (int p = 0; p < 4; ++p) {
                int kk = k + p * 8;
                float4 v = make_float4(0.f, 0.f, 0.f, 0.f);
                int n = n0 + n4;
                if (n + 3 < Nsz) {
                    v = *(const float4*)&Bm[(long)(kc + kk) * ldb + n];
                } else {
                    float tmp[4] = {0.f, 0.f, 0.f, 0.f};
                    for (int e = 0; e < 4; ++e)
                        if (n + e < Nsz) tmp[e] = Bm[(long)(kc + kk) * ldb + n + e];
                    v = make_float4(tmp[0], tmp[1], tmp[2], tmp[3]);
                }
                *(float4*)&Bl[kk][n4] = v;
            }
        }
        __syncthreads();
#pragma unroll 8
        for (int k = 0; k < 32; ++k) {
            float4 a0 = *(const float4*)&Al[k][ty * 4];
            float4 a1 = *(const float4*)&Al[k][ty * 4 + 64];
            float4 b0 = *(const float4*)&Bl[k][tx * 4];
            float4 b1 = *(const float4*)&Bl[k][tx * 4 + 64];
            float av[2][4] = {{a0.x, a0.y, a0.z, a0.w}, {a1.x, a1.y, a1.z, a1.w}};
            float bv[2][4] = {{b0.x, b0.y, b0.z, b0.w}, {b1.x, b1.y, b1.z, b1.w}};
#pragma unroll
            for (int ii = 0; ii < 2; ++ii)
#pragma unroll
                for (int jj = 0; jj < 2; ++jj)
#pragma unroll
                    for (int i = 0; i < 4; ++i)
#pragma unroll
                        for (int j = 0; j < 4; ++j)
                            acc[ii][jj][i][j] += av[ii][i] * bv[jj][j];
        }
        __syncthreads();
    }

#pragma unroll
    for (int ii = 0; ii < 2; ++ii)
#pragma unroll
        for (int i = 0; i < 4; ++i) {
            int m = m0 + ty * 4 + i + 64 * ii;
            if (m >= Msz) continue;
            float bval = 0.f;
            if (EPI >= 1) bval = bias[m];
#pragma unroll
            for (int jj = 0; jj < 2; ++jj) {
                int n = n0 + tx * 4 + 64 * jj;
                if (n >= Nsz) continue;
                float4 v = make_float4(acc[ii][jj][i][0], acc[ii][jj][i][1],
                                       acc[ii][jj][i][2], acc[ii][jj][i][3]);
                if (EPI >= 1) { v.x += bval; v.y += bval; v.z += bval; v.w += bval; }
                if (EPI == 2) {
                    float4 rx = *(const float4*)&res_x[((long)z * CC + m) * HWSZ + n];
                    float4 rg = *(const float4*)&res_g[(long)m * (BB * HWSZ) + (long)z * HWSZ + n];
                    v.x += rx.x + rg.x; v.y += rx.y + rg.y;
                    v.z += rx.z + rg.z; v.w += rx.w + rg.w;
                }
                if (n + 3 < Nsz) {
                    *(float4*)&Cc[(long)m * ldc + n] = v;
                } else {
                    float tmp[4] = {v.x, v.y, v.z, v.w};
                    for (int e = 0; e < 4; ++e)
                        if (n + e < Nsz) Cc[(long)m * ldc + n + e] = tmp[e];
                }
            }
        }
}

// ---------------- M = cv2_w[:,128:] @ out_proj_w  (128x256) ----------------
__global__ void computeM_kernel(const float* __restrict__ cv2_w,
                                const float* __restrict__ opw,
                                float* __restrict__ Mm)
{
    int o = blockIdx.x;
    int d = threadIdx.x;
    float acc = 0.f;
#pragma unroll 8
    for (int i = 0; i < CC; ++i)
        acc += cv2_w[o * 256 + 128 + i] * opw[i * 256 + d];
    Mm[o * 256 + d] = acc;
}

// ---------------- transpose + LayerNorm:  t_ln[b,l,c] ----------------
__global__ __launch_bounds__(256) void ln_kernel(const float* __restrict__ xh,
                                                 const float* __restrict__ ln_g,
                                                 const float* __restrict__ ln_b,
                                                 float* __restrict__ t_ln)
{
    __shared__ float tile[128][65];
    __shared__ float red[8][64];
    __shared__ float mean_s[64], inv_s[64];
    int b = blockIdx.y;
    int l0 = blockIdx.x * 64;
    int t = threadIdx.x;
#pragma unroll 4
    for (int p = 0; p < 32; ++p) {
        int c = (t / 64) + p * 4;
        tile[c][t % 64] = xh[((long)b * CC + c) * HWSZ + l0 + (t % 64)];
    }
    __syncthreads();
    int lc = t % 64, cg = t / 64;
    float s1 = 0.f, s2 = 0.f;
#pragma unroll 8
    for (int i = 0; i < 32; ++i) {
        float v = tile[cg * 32 + i][lc];
        s1 += v; s2 += v * v;
    }
    red[cg][lc] = s1;
    red[4 + cg][lc] = s2;
    __syncthreads();
    if (t < 64) {
        float m = (red[0][t] + red[1][t] + red[2][t] + red[3][t]) * (1.f / 128.f);
        float q = (red[4][t] + red[5][t] + red[6][t] + red[7][t]) * (1.f / 128.f);
        mean_s[t] = m;
        inv_s[t] = rsqrtf(q - m * m + 1e-5f);
    }
    __syncthreads();
#pragma unroll 4
    for (int p = 0; p < 32; ++p) {
        int c = t % 128;
        int lw = t / 128 + p * 2;
        float v = (tile[c][lw] - mean_s[lw]) * inv_s[lw] * ln_g[c] + ln_b[c];
        t_ln[((long)(b * LL + l0 + lw)) * CC + c] = v;
    }
}

// ---------------- local branch: dw3x3 + BN + SiLU ----------------
__global__ void dwconv_kernel(const float* __restrict__ xh,
                              const float* __restrict__ w9,
                              const float* __restrict__ bn_g,
                              const float* __restrict__ bn_b,
                              const float* __restrict__ bn_m,
                              const float* __restrict__ bn_v,
                              float* __restrict__ lbuf)
{
    long idx = (long)blockIdx.x * 256 + threadIdx.x;
    int hw = idx & (HWSZ - 1);
    int bc = idx >> 12;
    int c = bc & (CC - 1);
    int i = hw >> 6, j = hw & 63;
    const float* base = xh + (long)bc * HWSZ;
    float acc = 0.f;
#pragma unroll
    for (int u = 0; u < 3; ++u) {
        int ii = i + u - 1;
        if (ii < 0 || ii >= HH) continue;
#pragma unroll
        for (int v = 0; v < 3; ++v) {
            int jj = j + v - 1;
            if (jj < 0 || jj >= WW) continue;
            acc += base[ii * WW + jj] * w9[c * 9 + u * 3 + v];
        }
    }
    float sc = bn_g[c] * rsqrtf(bn_v[c] + 1e-5f);
    float val = (acc - bn_m[c]) * sc + bn_b[c];
    lbuf[idx] = silu_f(val);
}

// ---------------- causal depthwise conv1d (DC=4) + SiLU ----------------
__global__ void conv1d_kernel(const float* __restrict__ xz,
                              const float* __restrict__ cw,
                              const float* __restrict__ cb,
                              float* __restrict__ xm_act)
{
    int m = blockIdx.x;          // b*L + l
    int l = m & (LL - 1);
    int d = threadIdx.x;
    float acc = cb[d];
#pragma unroll
    for (int k = 0; k < 4; ++k) {
        int li = l + k - 3;
        if (li >= 0) acc += xz[((long)(m + k - 3)) * 512 + d] * cw[d * 4 + k];
    }
    xm_act[(long)m * DI + d] = silu_f(acc);
}

// ---------------- chunked selective scan, d-per-thread layout ----------------
// thread owns channel d (=threadIdx.x) and all DS=16 states in registers.
// dt projection (8-dot + softplus) fused in. No cross-lane ops at all.

// phase A: per-chunk partial state from h=0; emit hend[16] and sumdt
__global__ __launch_bounds__(256) void scanA_kernel(const float* __restrict__ xm_act,
                                                    const float* __restrict__ dbl,
                                                    const float* __restrict__ A_log,
                                                    const float* __restrict__ dpw,
                                                    const float* __restrict__ dpb,
                                                    float* __restrict__ hend,
                                                    float* __restrict__ sumdt_buf)
{
    const int chunk = blockIdx.x;
    const int b = blockIdx.y;
    const int d = threadIdx.x;

    float a[DS];
    {
        const float4* ap = (const float4*)&A_log[d * DS];
#pragma unroll
        for (int q = 0; q < 4; ++q) {
            float4 v = ap[q];
            a[q * 4 + 0] = -__expf(v.x);
            a[q * 4 + 1] = -__expf(v.y);
            a[q * 4 + 2] = -__expf(v.z);
            a[q * 4 + 3] = -__expf(v.w);
        }
    }
    float w[DR];
    {
        const float4* wp = (const float4*)&dpw[d * DR];
        float4 w0 = wp[0], w1 = wp[1];
        w[0] = w0.x; w[1] = w0.y; w[2] = w0.z; w[3] = w0.w;
        w[4] = w1.x; w[5] = w1.y; w[6] = w1.z; w[7] = w1.w;
    }
    const float bneg = dpb[d];

    float h[DS];
#pragma unroll
    for (int s = 0; s < DS; ++s) h[s] = 0.f;
    float sumdt = 0.f;

    const long m0 = (long)b * LL + chunk * CLEN;
#pragma unroll 4
    for (int l = 0; l < CLEN; ++l) {
        const long m = m0 + l;
        const float* row = dbl + m * NDBL;       // uniform across block
        float4 t0 = *(const float4*)(row);
        float4 t1 = *(const float4*)(row + 4);
        float dtv = bneg;
        dtv += t0.x * w[0] + t0.y * w[1] + t0.z * w[2] + t0.w * w[3];
        dtv += t1.x * w[4] + t1.y * w[5] + t1.z * w[6] + t1.w * w[7];
        dtv = softplus_f(dtv);
        sumdt += dtv;
        const float xm = xm_act[m * DI + d];
        const float t = dtv * xm;
        float Bv[DS];
#pragma unroll
        for (int q = 0; q < 4; ++q) {
            float4 v = *(const float4*)(row + DR + q * 4);
            Bv[q * 4 + 0] = v.x; Bv[q * 4 + 1] = v.y;
            Bv[q * 4 + 2] = v.z; Bv[q * 4 + 3] = v.w;
        }
#pragma unroll
        for (int s = 0; s < DS; ++s) {
            float da = __expf(dtv * a[s]);
            h[s] = da * h[s] + t * Bv[s];
        }
    }

    float* hb = hend + (((long)b * NCHUNK + chunk) * DI + d) * DS;
#pragma unroll
    for (int q = 0; q < 4; ++q)
        *(float4*)(hb + q * 4) = make_float4(h[q * 4], h[q * 4 + 1], h[q * 4 + 2], h[q * 4 + 3]);
    sumdt_buf[((long)b * NCHUNK + chunk) * DI + d] = sumdt;
}

// phase B: sequential combine across chunks. P[s] = exp(a[d,s]*sumdt).
__global__ __launch_bounds__(256) void scanB_kernel(const float* __restrict__ hend,
                                                    const float* __restrict__ sumdt_buf,
                                                    const float* __restrict__ A_log,
                                                    float* __restrict__ hinit)
{
    const int gid = blockIdx.x * 256 + threadIdx.x;   // 0..16383
    const int b = gid >> 12;
    const int col = gid & 4095;          // d*16 + s
    const int d = col >> 4;
    const int s = col & 15;
    const float a = -__expf(A_log[d * DS + s]);
    float hi = 0.f;
    for (int c = 0; c < NCHUNK; ++c) {
        const long base = ((long)b * NCHUNK + c) * 4096 + col;
        hinit[base] = hi;
        const float P = __expf(a * sumdt_buf[((long)b * NCHUNK + c) * DI + d]);
        hi = P * hi + hend[base];
    }
}

// phase C: recompute chunk with correct h0; emit gated output yg
__global__ __launch_bounds__(256) void scanC_kernel(const float* __restrict__ xm_act,
                                                    const float* __restrict__ dbl,
                                                    const float* __restrict__ xz,
                                                    const float* __restrict__ A_log,
                                                    const float* __restrict__ dpw,
                                                    const float* __restrict__ dpb,
                                                    const float* __restrict__ Dp,
                                                    const float* __restrict__ hinit,
                                                    float* __restrict__ yg)
{
    const int chunk = blockIdx.x;
    const int b = blockIdx.y;
    const int d = threadIdx.x;

    float a[DS];
    {
        const float4* ap = (const float4*)&A_log[d * DS];
#pragma unroll
        for (int q = 0; q < 4; ++q) {
            float4 v = ap[q];
            a[q * 4 + 0] = -__expf(v.x);
            a[q * 4 + 1] = -__expf(v.y);
            a[q * 4 + 2] = -__expf(v.z);
            a[q * 4 + 3] = -__expf(v.w);
        }
    }
    float w[DR];
    {
        const float4* wp = (const float4*)&dpw[d * DR];
        float4 w0 = wp[0], w1 = wp[1];
        w[0] = w0.x; w[1] = w0.y; w[2] = w0.z; w[3] = w0.w;
        w[4] = w1.x; w[5] = w1.y; w[6] = w1.z; w[7] = w1.w;
    }
    const float bneg = dpb[d];
    const float Dd = Dp[d];

    float h[DS];
    {
        const float* hb = hinit + ((long)b * NCHUNK + chunk) * 4096 + d * DS;
#pragma unroll
        for (int q = 0; q < 4; ++q) {
            float4 v = *(const float4*)(hb + q * 4);
            h[q * 4 + 0] = v.x; h[q * 4 + 1] = v.y;
            h[q * 4 + 2] = v.z; h[q * 4 + 3] = v.w;
        }
    }

    const long m0 = (long)b * LL + chunk * CLEN;
#pragma unroll 4
    for (int l = 0; l < CLEN; ++l) {
        const long m = m0 + l;
        const float* row = dbl + m * NDBL;
        float4 t0 = *(const float4*)(row);
        float4 t1 = *(const float4*)(row + 4);
        float dtv = bneg;
        dtv += t0.x * w[0] + t0.y * w[1] + t0.z * w[2] + t0.w * w[3];
        dtv += t1.x * w[4] + t1.y * w[5] + t1.z * w[6] + t1.w * w[7];
        dtv = softplus_f(dtv);
        const float xm = xm_act[m * DI + d];
        const float t = dtv * xm;
        float Bv[DS], Cv[DS];
#pragma unroll
        for (int q = 0; q < 4; ++q) {
            float4 v = *(const float4*)(row + DR + q * 4);
            Bv[q * 4 + 0] = v.x; Bv[q * 4 + 1] = v.y;
            Bv[q * 4 + 2] = v.z; Bv[q * 4 + 3] = v.w;
            float4 u = *(const float4*)(row + DR + DS + q * 4);
            Cv[q * 4 + 0] = u.x; Cv[q * 4 + 1] = u.y;
            Cv[q * 4 + 2] = u.z; Cv[q * 4 + 3] = u.w;
        }
        float p = 0.f;
#pragma unroll
        for (int s = 0; s < DS; ++s) {
            float da = __expf(dtv * a[s]);
            h[s] = da * h[s] + t * Bv[s];
            p += h[s] * Cv[s];
        }
        const float zv = xz[m * 512 + 256 + d];
        const float y = p + xm * Dd;
        yg[m * DI + d] = y * silu_f(zv);
    }
}

extern "C" void kernel_launch(void* const* d_in, const int* in_sizes, int n_in,
                              void* d_out, int out_size, void* d_ws, size_t ws_size,
                              hipStream_t stream)
{
    const float* x        = (const float*)d_in[0];
    const float* cv1_w    = (const float*)d_in[1];
    const float* cv1_b    = (const float*)d_in[2];
    const float* dw_w     = (const float*)d_in[3];
    const float* bn_g     = (const float*)d_in[4];
    const float* bn_b     = (const float*)d_in[5];
    const float* bn_m     = (const float*)d_in[6];
    const float* bn_v     = (const float*)d_in[7];
    const float* ln_g     = (const float*)d_in[8];
    const float* ln_b     = (const float*)d_in[9];
    const float* in_proj_w = (const float*)d_in[10];
    const float* conv1d_w = (const float*)d_in[11];
    const float* conv1d_b = (const float*)d_in[12];
    const float* x_proj_w = (const float*)d_in[13];
    const float* dt_proj_w = (const float*)d_in[14];
    const float* dt_proj_b = (const float*)d_in[15];
    const float* A_log    = (const float*)d_in[16];
    const float* Dp       = (const float*)d_in[17];
    const float* out_proj_w = (const float*)d_in[18];
    const float* cv2_w    = (const float*)d_in[19];
    const float* cv2_b    = (const float*)d_in[20];
    float* out = (float*)d_out;

    float* ws = (float*)d_ws;
    float* xh     = ws;                  // 2,097,152
    float* t_ln   = xh + 2097152;        // 2,097,152
    float* l_buf  = t_ln + 2097152;      // 2,097,152
    float* xz     = l_buf + 2097152;     // 8,388,608
    float* xm_act = xz + 8388608;        // 4,194,304
    float* dbl    = xm_act + 4194304;    // 655,360
    float* hinit  = dbl + 655360;        // 4,194,304
    float* yg     = hinit + 4194304;     // 4,194,304
    float* sumdt  = yg + 4194304;        // 262,144
    float* gpartT = sumdt + 262144;      // 2,097,152
    float* Mm     = gpartT + 2097152;    // 32,768
    // hend (4,194,304) aliases xh+t_ln: both dead after in_proj gemm,
    // which completes (stream-ordered) before scanA writes hend.
    float* hend   = xh;

    // fused cv2-global x out_proj matrix (independent)
    computeM_kernel<<<dim3(128), 256, 0, stream>>>(cv2_w, out_proj_w, Mm);

    // cv1: xh[b,o,hw] = cv1_w @ x[b] + cv1_b   (NN gemm, batched)
    gemm128<1, 1><<<dim3(32, 1, 4), 256, 0, stream>>>(
        cv1_w, 128, 0, x, HWSZ, (long)CC * HWSZ, xh, HWSZ, (long)CC * HWSZ,
        128, HWSZ, 128, cv1_b, nullptr, nullptr);

    // local branch
    dwconv_kernel<<<dim3(8192), 256, 0, stream>>>(xh, dw_w, bn_g, bn_b, bn_m, bn_v, l_buf);

    // transpose + LayerNorm
    ln_kernel<<<dim3(64, 4), 256, 0, stream>>>(xh, ln_g, ln_b, t_ln);

    // in_proj: xz[m, 0:512] = t_ln[m,:] @ in_proj_w^T  (NT gemm)
    gemm128<0, 0><<<dim3(4, 128, 1), 256, 0, stream>>>(
        t_ln, 128, 0, in_proj_w, 128, 0, xz, 512, 0,
        16384, 512, 128, nullptr, nullptr, nullptr);

    // causal depthwise conv1d + silu
    conv1d_kernel<<<dim3(16384), 256, 0, stream>>>(xz, conv1d_w, conv1d_b, xm_act);

    // x_proj: dbl[m, 0:40] = xm_act[m,:] @ x_proj_w^T
    gemm128<0, 0><<<dim3(1, 128, 1), 256, 0, stream>>>(
        xm_act, 256, 0, x_proj_w, 256, 0, dbl, NDBL, 0,
        16384, NDBL, 256, nullptr, nullptr, nullptr);

    // chunked selective scan (dt-projection fused inside)
    scanA_kernel<<<dim3(NCHUNK, BB), 256, 0, stream>>>(
        xm_act, dbl, A_log, dt_proj_w, dt_proj_b, hend, sumdt);
    scanB_kernel<<<dim3(64), 256, 0, stream>>>(hend, sumdt, A_log, hinit);
    scanC_kernel<<<dim3(NCHUNK, BB), 256, 0, stream>>>(
        xm_act, dbl, xz, A_log, dt_proj_w, dt_proj_b, Dp, hinit, yg);

    // g_part: gpartT[o, b*hw] = M[o,:] @ yg[m,:]^T  (NT gemm, M rows = 128)
    gemm128<0, 0><<<dim3(128, 1, 1), 256, 0, stream>>>(
        Mm, 256, 0, yg, 256, 0, gpartT, BB * HWSZ, 0,
        128, BB * HWSZ, 256, nullptr, nullptr, nullptr);

    // final: out[b,o,hw] = x + cv2_b[o] + cv2_w[:, :128] @ l_buf[b] + gpartT
    gemm128<2, 1><<<dim3(32, 1, 4), 256, 0, stream>>>(
        cv2_w, 256, 0, l_buf, HWSZ, (long)CC * HWSZ, out, HWSZ, (long)CC * HWSZ,
        128, HWSZ, 128, cv2_b, x, gpartT);
}

// Round 3
// 216.317 us; speedup vs baseline: 1.7994x; 1.4925x over previous
//
#include <hip/hip_runtime.h>
#include <hip/hip_bf16.h>

#define BB 4
#define CC 128
#define HH 64
#define WW 64
#define HWSZ 4096
#define LL 4096
#define DI 256
#define DS 16
#define DR 8
#define NDBL 40
#define NCHUNK 256
#define CLEN 16

__device__ __forceinline__ float silu_f(float x) {
    return x / (1.f + __expf(-x));
}
__device__ __forceinline__ float softplus_f(float x) {
    return (x > 20.f) ? x : log1pf(__expf(x));
}

// ---------------- Generic 64x64-tile fp32 GEMM ----------------
// C[m,n] = sum_k A[m,k] * B(n,k).  BKN=0: B is [N][K] row-major (NT).
// BKN=1: B is [K][N] row-major (NN).  EPI: 0=plain, 1=+bias[m].
template<int EPI, int BKN>
__global__ __launch_bounds__(256) void gemm64(
    const float* __restrict__ Ap, int lda, long aStr,
    const float* __restrict__ Bp, int ldb, long bStr,
    float* __restrict__ Cp, int ldc, long cStr,
    int Msz, int Nsz, int Ksz,
    const float* __restrict__ bias)
{
    __shared__ float Al[32][68];
    __shared__ float Bl[32][68];
    const int tid = threadIdx.x;
    const int z = blockIdx.z;
    const int m0 = blockIdx.y * 64;
    const int n0 = blockIdx.x * 64;
    const float* A = Ap + (long)z * aStr;
    const float* Bm = Bp + (long)z * bStr;
    float* Cc = Cp + (long)z * cStr;
    const int ty = tid / 16, tx = tid % 16;

    float acc[4][4];
#pragma unroll
    for (int i = 0; i < 4; ++i)
#pragma unroll
        for (int j = 0; j < 4; ++j) acc[i][j] = 0.f;

    for (int kc = 0; kc < Ksz; kc += 32) {
        // stage A tile (64 m x 32 k) -> Al[k][m]
#pragma unroll
        for (int p = 0; p < 2; ++p) {
            int ml = tid / 8 + p * 32;
            int m = m0 + ml;
            int c4 = (tid % 8) * 4;
            float4 v = make_float4(0.f, 0.f, 0.f, 0.f);
            if (m < Msz) v = *(const float4*)&A[(long)m * lda + kc + c4];
            Al[c4 + 0][ml] = v.x;
            Al[c4 + 1][ml] = v.y;
            Al[c4 + 2][ml] = v.z;
            Al[c4 + 3][ml] = v.w;
        }
        if (BKN == 0) {
#pragma unroll
            for (int p = 0; p < 2; ++p) {
                int nl = tid / 8 + p * 32;
                int n = n0 + nl;
                int c4 = (tid % 8) * 4;
                float4 v = make_float4(0.f, 0.f, 0.f, 0.f);
                if (n < Nsz) v = *(const float4*)&Bm[(long)n * ldb + kc + c4];
                Bl[c4 + 0][nl] = v.x;
                Bl[c4 + 1][nl] = v.y;
                Bl[c4 + 2][nl] = v.z;
                Bl[c4 + 3][nl] = v.w;
            }
        } else {
#pragma unroll
            for (int p = 0; p < 2; ++p) {
                int kk = tid / 16 + p * 16;
                int n4 = (tid % 16) * 4;
                float4 v = *(const float4*)&Bm[(long)(kc + kk) * ldb + n0 + n4];
                *(float4*)&Bl[kk][n4] = v;
            }
        }
        __syncthreads();
#pragma unroll
        for (int k = 0; k < 32; ++k) {
            float4 a = *(const float4*)&Al[k][ty * 4];
            float4 b = *(const float4*)&Bl[k][tx * 4];
            float av[4] = {a.x, a.y, a.z, a.w};
            float bv[4] = {b.x, b.y, b.z, b.w};
#pragma unroll
            for (int i = 0; i < 4; ++i)
#pragma unroll
                for (int j = 0; j < 4; ++j)
                    acc[i][j] += av[i] * bv[j];
        }
        __syncthreads();
    }

#pragma unroll
    for (int i = 0; i < 4; ++i) {
        int m = m0 + ty * 4 + i;
        if (m >= Msz) continue;
        float bval = (EPI >= 1) ? bias[m] : 0.f;
        int n = n0 + tx * 4;
        if (n >= Nsz) continue;
        float4 v = make_float4(acc[i][0] + bval, acc[i][1] + bval,
                               acc[i][2] + bval, acc[i][3] + bval);
        if (n + 3 < Nsz) {
            *(float4*)&Cc[(long)m * ldc + n] = v;
        } else {
            float tmp[4] = {v.x, v.y, v.z, v.w};
            for (int e = 0; e < 4; ++e)
                if (n + e < Nsz) Cc[(long)m * ldc + n + e] = tmp[e];
        }
    }
}

// ---------------- fused output GEMM: out = x + cv2_b + Acat @ Bcat ----------------
// Acat[128][384] = [cv2_w[:, :128] | cv2_w[:,128:] @ out_proj_w]
// Bcat[k][n]: k<128 -> l_buf[b][k][hw];  k>=128 -> yg[n][k-128]
__global__ __launch_bounds__(256) void gemm_out_kernel(
    const float* __restrict__ Acat,
    const float* __restrict__ l_buf,
    const float* __restrict__ yg,
    const float* __restrict__ cv2_b,
    const float* __restrict__ x,
    float* __restrict__ outp)
{
    __shared__ float Al[32][68];
    __shared__ float Bl[32][68];
    const int tid = threadIdx.x;
    const int m0 = blockIdx.y * 64;
    const int b = blockIdx.x >> 6;          // 64 n-tiles per batch
    const int hw0 = (blockIdx.x & 63) * 64;
    const int ty = tid / 16, tx = tid % 16;

    float acc[4][4];
#pragma unroll
    for (int i = 0; i < 4; ++i)
#pragma unroll
        for (int j = 0; j < 4; ++j) acc[i][j] = 0.f;

    for (int kc = 0; kc < 384; kc += 32) {
#pragma unroll
        for (int p = 0; p < 2; ++p) {
            int ml = tid / 8 + p * 32;
            int c4 = (tid % 8) * 4;
            float4 v = *(const float4*)&Acat[(long)(m0 + ml) * 384 + kc + c4];
            Al[c4 + 0][ml] = v.x;
            Al[c4 + 1][ml] = v.y;
            Al[c4 + 2][ml] = v.z;
            Al[c4 + 3][ml] = v.w;
        }
        if (kc < 128) {
            // from l_buf [b][128][4096]
#pragma unroll
            for (int p = 0; p < 2; ++p) {
                int kk = tid / 16 + p * 16;
                int n4 = (tid % 16) * 4;
                float4 v = *(const float4*)&l_buf[((long)b * CC + kc + kk) * HWSZ + hw0 + n4];
                *(float4*)&Bl[kk][n4] = v;
            }
        } else {
            // from yg [b*4096+hw][256]
#pragma unroll
            for (int p = 0; p < 2; ++p) {
                int nl = tid / 8 + p * 32;
                int c4 = (tid % 8) * 4;
                float4 v = *(const float4*)&yg[((long)b * HWSZ + hw0 + nl) * DI + (kc - 128) + c4];
                Bl[c4 + 0][nl] = v.x;
                Bl[c4 + 1][nl] = v.y;
                Bl[c4 + 2][nl] = v.z;
                Bl[c4 + 3][nl] = v.w;
            }
        }
        __syncthreads();
#pragma unroll
        for (int k = 0; k < 32; ++k) {
            float4 a = *(const float4*)&Al[k][ty * 4];
            float4 b4 = *(const float4*)&Bl[k][tx * 4];
            float av[4] = {a.x, a.y, a.z, a.w};
            float bv[4] = {b4.x, b4.y, b4.z, b4.w};
#pragma unroll
            for (int i = 0; i < 4; ++i)
#pragma unroll
                for (int j = 0; j < 4; ++j)
                    acc[i][j] += av[i] * bv[j];
        }
        __syncthreads();
    }

#pragma unroll
    for (int i = 0; i < 4; ++i) {
        int o = m0 + ty * 4 + i;
        float bval = cv2_b[o];
        long base = ((long)b * CC + o) * HWSZ + hw0 + tx * 4;
        float4 rx = *(const float4*)&x[base];
        float4 v = make_float4(acc[i][0] + bval + rx.x, acc[i][1] + bval + rx.y,
                               acc[i][2] + bval + rx.z, acc[i][3] + bval + rx.w);
        *(float4*)&outp[base] = v;
    }
}

// ---------------- Acat = [cv2_w[:, :128] | cv2_w[:,128:] @ out_proj_w] ----------------
__global__ void acat_kernel(const float* __restrict__ cv2_w,
                            const float* __restrict__ opw,
                            float* __restrict__ Acat)
{
    int o = blockIdx.x;
    int t = threadIdx.x;
    if (t < 128) {
        Acat[(long)o * 384 + t] = cv2_w[o * 256 + t];
    } else {
        int d = t - 128;
        float acc = 0.f;
#pragma unroll 8
        for (int i = 0; i < CC; ++i)
            acc += cv2_w[o * 256 + 128 + i] * opw[i * 256 + d];
        Acat[(long)o * 384 + 128 + d] = acc;
    }
}

// ---------------- transpose + LayerNorm:  t_ln[b,l,c] ----------------
__global__ __launch_bounds__(256) void ln_kernel(const float* __restrict__ xh,
                                                 const float* __restrict__ ln_g,
                                                 const float* __restrict__ ln_b,
                                                 float* __restrict__ t_ln)
{
    __shared__ float tile[128][65];
    __shared__ float red[8][64];
    __shared__ float mean_s[64], inv_s[64];
    int b = blockIdx.y;
    int l0 = blockIdx.x * 64;
    int t = threadIdx.x;
#pragma unroll 4
    for (int p = 0; p < 32; ++p) {
        int c = (t / 64) + p * 4;
        tile[c][t % 64] = xh[((long)b * CC + c) * HWSZ + l0 + (t % 64)];
    }
    __syncthreads();
    int lc = t % 64, cg = t / 64;
    float s1 = 0.f, s2 = 0.f;
#pragma unroll 8
    for (int i = 0; i < 32; ++i) {
        float v = tile[cg * 32 + i][lc];
        s1 += v; s2 += v * v;
    }
    red[cg][lc] = s1;
    red[4 + cg][lc] = s2;
    __syncthreads();
    if (t < 64) {
        float m = (red[0][t] + red[1][t] + red[2][t] + red[3][t]) * (1.f / 128.f);
        float q = (red[4][t] + red[5][t] + red[6][t] + red[7][t]) * (1.f / 128.f);
        mean_s[t] = m;
        inv_s[t] = rsqrtf(q - m * m + 1e-5f);
    }
    __syncthreads();
#pragma unroll 4
    for (int p = 0; p < 32; ++p) {
        int c = t % 128;
        int lw = t / 128 + p * 2;
        float v = (tile[c][lw] - mean_s[lw]) * inv_s[lw] * ln_g[c] + ln_b[c];
        t_ln[((long)(b * LL + l0 + lw)) * CC + c] = v;
    }
}

// ---------------- local branch: dw3x3 + BN + SiLU ----------------
__global__ void dwconv_kernel(const float* __restrict__ xh,
                              const float* __restrict__ w9,
                              const float* __restrict__ bn_g,
                              const float* __restrict__ bn_b,
                              const float* __restrict__ bn_m,
                              const float* __restrict__ bn_v,
                              float* __restrict__ lbuf)
{
    long idx = (long)blockIdx.x * 256 + threadIdx.x;
    int hw = idx & (HWSZ - 1);
    int bc = idx >> 12;
    int c = bc & (CC - 1);
    int i = hw >> 6, j = hw & 63;
    const float* base = xh + (long)bc * HWSZ;
    float acc = 0.f;
#pragma unroll
    for (int u = 0; u < 3; ++u) {
        int ii = i + u - 1;
        if (ii < 0 || ii >= HH) continue;
#pragma unroll
        for (int v = 0; v < 3; ++v) {
            int jj = j + v - 1;
            if (jj < 0 || jj >= WW) continue;
            acc += base[ii * WW + jj] * w9[c * 9 + u * 3 + v];
        }
    }
    float sc = bn_g[c] * rsqrtf(bn_v[c] + 1e-5f);
    float val = (acc - bn_m[c]) * sc + bn_b[c];
    lbuf[idx] = silu_f(val);
}

// ---------------- causal depthwise conv1d (DC=4) + SiLU, rolling window ----------------
__global__ __launch_bounds__(256) void conv1d_kernel(const float* __restrict__ xz,
                                                     const float* __restrict__ cw,
                                                     const float* __restrict__ cb,
                                                     float* __restrict__ xm_act)
{
    const int b = blockIdx.y;
    const int l0 = blockIdx.x * 32;
    const int d = threadIdx.x;
    const float4 w = *(const float4*)&cw[d * 4];
    const float bias = cb[d];
    float x0 = 0.f, x1 = 0.f, x2 = 0.f;
    const long rowBase = ((long)b * LL + l0) * 512 + d;
    if (l0 >= 3) {
        x0 = xz[rowBase - 3 * 512];
        x1 = xz[rowBase - 2 * 512];
        x2 = xz[rowBase - 1 * 512];
    }
    long outBase = ((long)b * LL + l0) * DI + d;
#pragma unroll 8
    for (int l = 0; l < 32; ++l) {
        float xl = xz[rowBase + (long)l * 512];
        float acc = bias + x0 * w.x + x1 * w.y + x2 * w.z + xl * w.w;
        xm_act[outBase + (long)l * DI] = silu_f(acc);
        x0 = x1; x1 = x2; x2 = xl;
    }
}

// ---------------- chunked selective scan, d-per-thread layout ----------------
__global__ __launch_bounds__(256) void scanA_kernel(const float* __restrict__ xm_act,
                                                    const float* __restrict__ dbl,
                                                    const float* __restrict__ A_log,
                                                    const float* __restrict__ dpw,
                                                    const float* __restrict__ dpb,
                                                    float* __restrict__ hend,
                                                    float* __restrict__ sumdt_buf)
{
    const int chunk = blockIdx.x;
    const int b = blockIdx.y;
    const int d = threadIdx.x;

    float a[DS];
    {
        const float4* ap = (const float4*)&A_log[d * DS];
#pragma unroll
        for (int q = 0; q < 4; ++q) {
            float4 v = ap[q];
            a[q * 4 + 0] = -__expf(v.x);
            a[q * 4 + 1] = -__expf(v.y);
            a[q * 4 + 2] = -__expf(v.z);
            a[q * 4 + 3] = -__expf(v.w);
        }
    }
    float w[DR];
    {
        const float4* wp = (const float4*)&dpw[d * DR];
        float4 w0 = wp[0], w1 = wp[1];
        w[0] = w0.x; w[1] = w0.y; w[2] = w0.z; w[3] = w0.w;
        w[4] = w1.x; w[5] = w1.y; w[6] = w1.z; w[7] = w1.w;
    }
    const float bneg = dpb[d];

    float h[DS];
#pragma unroll
    for (int s = 0; s < DS; ++s) h[s] = 0.f;
    float sumdt = 0.f;

    const long m0 = (long)b * LL + chunk * CLEN;
#pragma unroll 4
    for (int l = 0; l < CLEN; ++l) {
        const long m = m0 + l;
        const float* row = dbl + m * NDBL;
        float4 t0 = *(const float4*)(row);
        float4 t1 = *(const float4*)(row + 4);
        float dtv = bneg;
        dtv += t0.x * w[0] + t0.y * w[1] + t0.z * w[2] + t0.w * w[3];
        dtv += t1.x * w[4] + t1.y * w[5] + t1.z * w[6] + t1.w * w[7];
        dtv = softplus_f(dtv);
        sumdt += dtv;
        const float xm = xm_act[m * DI + d];
        const float t = dtv * xm;
        float Bv[DS];
#pragma unroll
        for (int q = 0; q < 4; ++q) {
            float4 v = *(const float4*)(row + DR + q * 4);
            Bv[q * 4 + 0] = v.x; Bv[q * 4 + 1] = v.y;
            Bv[q * 4 + 2] = v.z; Bv[q * 4 + 3] = v.w;
        }
#pragma unroll
        for (int s = 0; s < DS; ++s) {
            float da = __expf(dtv * a[s]);
            h[s] = da * h[s] + t * Bv[s];
        }
    }

    float* hb = hend + (((long)b * NCHUNK + chunk) * DI + d) * DS;
#pragma unroll
    for (int q = 0; q < 4; ++q)
        *(float4*)(hb + q * 4) = make_float4(h[q * 4], h[q * 4 + 1], h[q * 4 + 2], h[q * 4 + 3]);
    sumdt_buf[((long)b * NCHUNK + chunk) * DI + d] = sumdt;
}

__global__ __launch_bounds__(256) void scanB_kernel(const float* __restrict__ hend,
                                                    const float* __restrict__ sumdt_buf,
                                                    const float* __restrict__ A_log,
                                                    float* __restrict__ hinit)
{
    const int gid = blockIdx.x * 256 + threadIdx.x;   // 0..16383
    const int b = gid >> 12;
    const int col = gid & 4095;          // d*16 + s
    const int d = col >> 4;
    const int s = col & 15;
    const float a = -__expf(A_log[d * DS + s]);
    float hi = 0.f;
    for (int c = 0; c < NCHUNK; ++c) {
        const long base = ((long)b * NCHUNK + c) * 4096 + col;
        hinit[base] = hi;
        const float P = __expf(a * sumdt_buf[((long)b * NCHUNK + c) * DI + d]);
        hi = P * hi + hend[base];
    }
}

__global__ __launch_bounds__(256) void scanC_kernel(const float* __restrict__ xm_act,
                                                    const float* __restrict__ dbl,
                                                    const float* __restrict__ xz,
                                                    const float* __restrict__ A_log,
                                                    const float* __restrict__ dpw,
                                                    const float* __restrict__ dpb,
                                                    const float* __restrict__ Dp,
                                                    const float* __restrict__ hinit,
                                                    float* __restrict__ yg)
{
    const int chunk = blockIdx.x;
    const int b = blockIdx.y;
    const int d = threadIdx.x;

    float a[DS];
    {
        const float4* ap = (const float4*)&A_log[d * DS];
#pragma unroll
        for (int q = 0; q < 4; ++q) {
            float4 v = ap[q];
            a[q * 4 + 0] = -__expf(v.x);
            a[q * 4 + 1] = -__expf(v.y);
            a[q * 4 + 2] = -__expf(v.z);
            a[q * 4 + 3] = -__expf(v.w);
        }
    }
    float w[DR];
    {
        const float4* wp = (const float4*)&dpw[d * DR];
        float4 w0 = wp[0], w1 = wp[1];
        w[0] = w0.x; w[1] = w0.y; w[2] = w0.z; w[3] = w0.w;
        w[4] = w1.x; w[5] = w1.y; w[6] = w1.z; w[7] = w1.w;
    }
    const float bneg = dpb[d];
    const float Dd = Dp[d];

    float h[DS];
    {
        const float* hb = hinit + ((long)b * NCHUNK + chunk) * 4096 + d * DS;
#pragma unroll
        for (int q = 0; q < 4; ++q) {
            float4 v = *(const float4*)(hb + q * 4);
            h[q * 4 + 0] = v.x; h[q * 4 + 1] = v.y;
            h[q * 4 + 2] = v.z; h[q * 4 + 3] = v.w;
        }
    }

    const long m0 = (long)b * LL + chunk * CLEN;
#pragma unroll 4
    for (int l = 0; l < CLEN; ++l) {
        const long m = m0 + l;
        const float* row = dbl + m * NDBL;
        float4 t0 = *(const float4*)(row);
        float4 t1 = *(const float4*)(row + 4);
        float dtv = bneg;
        dtv += t0.x * w[0] + t0.y * w[1] + t0.z * w[2] + t0.w * w[3];
        dtv += t1.x * w[4] + t1.y * w[5] + t1.z * w[6] + t1.w * w[7];
        dtv = softplus_f(dtv);
        const float xm = xm_act[m * DI + d];
        const float t = dtv * xm;
        float Bv[DS], Cv[DS];
#pragma unroll
        for (int q = 0; q < 4; ++q) {
            float4 v = *(const float4*)(row + DR + q * 4);
            Bv[q * 4 + 0] = v.x; Bv[q * 4 + 1] = v.y;
            Bv[q * 4 + 2] = v.z; Bv[q * 4 + 3] = v.w;
            float4 u = *(const float4*)(row + DR + DS + q * 4);
            Cv[q * 4 + 0] = u.x; Cv[q * 4 + 1] = u.y;
            Cv[q * 4 + 2] = u.z; Cv[q * 4 + 3] = u.w;
        }
        float p = 0.f;
#pragma unroll
        for (int s = 0; s < DS; ++s) {
            float da = __expf(dtv * a[s]);
            h[s] = da * h[s] + t * Bv[s];
            p += h[s] * Cv[s];
        }
        const float zv = xz[m * 512 + 256 + d];
        const float y = p + xm * Dd;
        yg[m * DI + d] = y * silu_f(zv);
    }
}

extern "C" void kernel_launch(void* const* d_in, const int* in_sizes, int n_in,
                              void* d_out, int out_size, void* d_ws, size_t ws_size,
                              hipStream_t stream)
{
    const float* x        = (const float*)d_in[0];
    const float* cv1_w    = (const float*)d_in[1];
    const float* cv1_b    = (const float*)d_in[2];
    const float* dw_w     = (const float*)d_in[3];
    const float* bn_g     = (const float*)d_in[4];
    const float* bn_b     = (const float*)d_in[5];
    const float* bn_m     = (const float*)d_in[6];
    const float* bn_v     = (const float*)d_in[7];
    const float* ln_g     = (const float*)d_in[8];
    const float* ln_b     = (const float*)d_in[9];
    const float* in_proj_w = (const float*)d_in[10];
    const float* conv1d_w = (const float*)d_in[11];
    const float* conv1d_b = (const float*)d_in[12];
    const float* x_proj_w = (const float*)d_in[13];
    const float* dt_proj_w = (const float*)d_in[14];
    const float* dt_proj_b = (const float*)d_in[15];
    const float* A_log    = (const float*)d_in[16];
    const float* Dp       = (const float*)d_in[17];
    const float* out_proj_w = (const float*)d_in[18];
    const float* cv2_w    = (const float*)d_in[19];
    const float* cv2_b    = (const float*)d_in[20];
    float* out = (float*)d_out;

    float* ws = (float*)d_ws;
    float* xh     = ws;                  // 2,097,152
    float* t_ln   = xh + 2097152;        // 2,097,152
    float* l_buf  = t_ln + 2097152;      // 2,097,152
    float* xz     = l_buf + 2097152;     // 8,388,608
    float* xm_act = xz + 8388608;        // 4,194,304
    float* dbl    = xm_act + 4194304;    // 655,360
    float* hinit  = dbl + 655360;        // 4,194,304
    float* yg     = hinit + 4194304;     // 4,194,304
    float* sumdt  = yg + 4194304;        // 262,144
    float* Acat   = sumdt + 262144;      // 49,152
    // hend (4,194,304) aliases xh+t_ln: both dead after in_proj gemm,
    // which completes (stream-ordered) before scanA writes hend.
    float* hend   = xh;

    // Acat = [cv2_w_local | cv2_w_global @ out_proj_w]
    acat_kernel<<<dim3(128), 384, 0, stream>>>(cv2_w, out_proj_w, Acat);

    // cv1: xh[b,o,hw] = cv1_w @ x[b] + cv1_b   (NN, batched)
    gemm64<1, 1><<<dim3(64, 2, 4), 256, 0, stream>>>(
        cv1_w, 128, 0, x, HWSZ, (long)CC * HWSZ, xh, HWSZ, (long)CC * HWSZ,
        128, HWSZ, 128, cv1_b);

    // local branch
    dwconv_kernel<<<dim3(8192), 256, 0, stream>>>(xh, dw_w, bn_g, bn_b, bn_m, bn_v, l_buf);

    // transpose + LayerNorm
    ln_kernel<<<dim3(64, 4), 256, 0, stream>>>(xh, ln_g, ln_b, t_ln);

    // in_proj: xz[m, 0:512] = t_ln[m,:] @ in_proj_w^T  (NT)
    gemm64<0, 0><<<dim3(8, 256, 1), 256, 0, stream>>>(
        t_ln, 128, 0, in_proj_w, 128, 0, xz, 512, 0,
        16384, 512, 128, nullptr);

    // causal depthwise conv1d + silu (rolling window)
    conv1d_kernel<<<dim3(128, 4), 256, 0, stream>>>(xz, conv1d_w, conv1d_b, xm_act);

    // x_proj: dbl[m, 0:40] = xm_act[m,:] @ x_proj_w^T  (NT, N=40 padded in-kernel)
    gemm64<0, 0><<<dim3(1, 256, 1), 256, 0, stream>>>(
        xm_act, 256, 0, x_proj_w, 256, 0, dbl, NDBL, 0,
        16384, NDBL, 256, nullptr);

    // chunked selective scan (dt-projection fused inside)
    scanA_kernel<<<dim3(NCHUNK, BB), 256, 0, stream>>>(
        xm_act, dbl, A_log, dt_proj_w, dt_proj_b, hend, sumdt);
    scanB_kernel<<<dim3(64), 256, 0, stream>>>(hend, sumdt, A_log, hinit);
    scanC_kernel<<<dim3(NCHUNK, BB), 256, 0, stream>>>(
        xm_act, dbl, xz, A_log, dt_proj_w, dt_proj_b, Dp, hinit, yg);

    // fused output: out = x + cv2_b + cv2_w_local @ l_buf + M @ yg^T
    gemm_out_kernel<<<dim3(256, 2), 256, 0, stream>>>(
        Acat, l_buf, yg, cv2_b, x, out);
}